// Round 8
// baseline (209.539 us; speedup 1.0000x reference)
//
#include <hip/hip_runtime.h>
#include <hip/hip_fp16.h>

#define N_NODES 50000
#define N_EDGES 800000
#define D 64
#define DHID 100
#define NTILES (N_NODES / 16)                   // 3125
#define NCT 7                                   // head col-tiles (112 cols padded)
#define CAP 32                                  // slots per node = ONE 128B csr line
#define SPILL_MAX 8192                          // overflow edges (exp ~20)
#define NGROUPS 4                               // dst-range groups
#define NSLICES 780                             // fill blocks per group
#define FILL_BLOCKS (NGROUPS * NSLICES)         // 3120
#define MM_BLOCKS ((NTILES + 3) / 4)            // 782
#define DST_PER_GROUP (N_NODES / NGROUPS)       // 12500
#define FSTRIDE (NSLICES * 256)                 // 199680
#define KMAX 5                                  // scan iterations per thread
#define GP_BLOCKS 6250                          // gather-pass grid (8 nodes/block)

typedef unsigned short ushort;
typedef unsigned int uint;
typedef __attribute__((ext_vector_type(8))) short s16x8;
typedef __attribute__((ext_vector_type(4))) float f32x4;
typedef __attribute__((ext_vector_type(4))) uint u32x4;

#define MFMA16(A, B, C) __builtin_amdgcn_mfma_f32_16x16x32_bf16((A), (B), (C), 0, 0, 0)

__device__ __forceinline__ float swishf(float x) { return x / (1.0f + __expf(-x)); }

__device__ __forceinline__ ushort f2bf(float f) {   // RTNE fp32 -> bf16
    uint u = __float_as_uint(f);
    uint r = (u + 0x7fffu + ((u >> 16) & 1u)) >> 16;
    return (ushort)r;
}
__device__ __forceinline__ float bf2f(ushort h) { return __uint_as_float((uint)h << 16); }
__device__ __forceinline__ float bf_lo(uint d) { return __uint_as_float(d << 16); }
__device__ __forceinline__ float bf_hi(uint d) { return __uint_as_float(d & 0xffff0000u); }

__device__ __forceinline__ float hwf(uint e) {
    return __half2float(__ushort_as_half((ushort)(e >> 16)));
}

__device__ __forceinline__ void accum8(float* acc, uint4 v, float w) {
    acc[0] = fmaf(w, bf_lo(v.x), acc[0]);
    acc[1] = fmaf(w, bf_hi(v.x), acc[1]);
    acc[2] = fmaf(w, bf_lo(v.y), acc[2]);
    acc[3] = fmaf(w, bf_hi(v.y), acc[3]);
    acc[4] = fmaf(w, bf_lo(v.z), acc[4]);
    acc[5] = fmaf(w, bf_hi(v.z), acc[5]);
    acc[6] = fmaf(w, bf_lo(v.w), acc[6]);
    acc[7] = fmaf(w, bf_hi(v.w), acc[7]);
}

// XCD-chunked bijective block swizzle for GP_BLOCKS=6250 (q=781, r=2):
// bid&7 -> XCD under round-robin dispatch; each XCD gets a CONTIGUOUS node
// range so its csr/act slices are XCD-local.
__device__ __forceinline__ int swz6250(int bid) {
    int x = bid & 7, ix = bid >> 3;
    return x * 781 + (x < 2 ? x : 2) + ix;
}

// Plane gather: one 32-feature plane (64B rows, 3.2MB -> fits per-XCD L2).
// lane = h(1b: node) x j(3b: slot-quad, 8x4=32 slots) x fgp(2b: 16B feature grp).
// acc[8] = this lane's 8 features; reduced over j (xor 4,8,16).
__device__ __forceinline__ void gather32(const ushort* __restrict__ plane,
                                         const uint* __restrict__ bucket,
                                         int degv, int sj, int fgp, float* acc) {
#pragma unroll
    for (int t = 0; t < 8; ++t) acc[t] = 0.f;
    if (sj < degv) {
        uint4 e = *((const uint4*)(bucket + sj));
        float w0 = hwf(e.x);
        float w1 = (sj + 1 < degv) ? hwf(e.y) : 0.f;
        float w2 = (sj + 2 < degv) ? hwf(e.z) : 0.f;
        float w3 = (sj + 3 < degv) ? hwf(e.w) : 0.f;
        uint i0 = min(e.x & 0xffffu, (uint)(N_NODES - 1));
        uint i1 = min(e.y & 0xffffu, (uint)(N_NODES - 1));
        uint i2 = min(e.z & 0xffffu, (uint)(N_NODES - 1));
        uint i3 = min(e.w & 0xffffu, (uint)(N_NODES - 1));
        uint4 v0 = *((const uint4*)(plane + ((size_t)i0 << 5) + (fgp << 3)));
        uint4 v1 = *((const uint4*)(plane + ((size_t)i1 << 5) + (fgp << 3)));
        uint4 v2 = *((const uint4*)(plane + ((size_t)i2 << 5) + (fgp << 3)));
        uint4 v3 = *((const uint4*)(plane + ((size_t)i3 << 5) + (fgp << 3)));
        accum8(acc, v0, w0);
        accum8(acc, v1, w1);
        accum8(acc, v2, w2);
        accum8(acc, v3, w3);
    }
#pragma unroll
    for (int t = 0; t < 8; ++t) {
        acc[t] += __shfl_xor(acc[t], 4, 64);
        acc[t] += __shfl_xor(acc[t], 8, 64);
        acc[t] += __shfl_xor(acc[t], 16, 64);
    }
}

// Overflow edges (slot >= CAP in fill); j==0 lanes, after the reduce.
__device__ __forceinline__ void add_spills32(const ushort* __restrict__ plane,
                                             const int* __restrict__ spillCnt,
                                             const uint2* __restrict__ spill,
                                             int node, int fgp, float* acc) {
    int n = min(*spillCnt, SPILL_MAX);
    for (int i = 0; i < n; ++i) {
        uint2 sp = spill[i];
        if ((int)sp.x == node) {
            float wv = hwf(sp.y);
            uint si = min(sp.y & 0xffffu, (uint)(N_NODES - 1));
            uint4 v = *((const uint4*)(plane + ((size_t)si << 5) + (fgp << 3)));
            accum8(acc, v, wv);
        }
    }
}

// ---- fused: XCD-partitioned fill + H1 = X@W1 (plane-split) + weight prep ----
__global__ __launch_bounds__(256) void fill_and_l1(const int* __restrict__ src,
                                                   const int* __restrict__ dst,
                                                   const float* __restrict__ w,
                                                   int* __restrict__ deg,
                                                   uint* __restrict__ csr,
                                                   int* __restrict__ spillCnt,
                                                   uint2* __restrict__ spill,
                                                   const float* __restrict__ X,
                                                   const float* __restrict__ W,
                                                   const float* __restrict__ W2,
                                                   const float* __restrict__ Wd,
                                                   short* __restrict__ W2T2,
                                                   short* __restrict__ WdT2,
                                                   ushort* __restrict__ H1a,
                                                   ushort* __restrict__ H1b) {
    __shared__ __align__(16) short sBT[2][D][72];    // 18.4 KB (aliased as rep later)
    int tid = threadIdx.x;

    if (blockIdx.x < FILL_BLOCKS) {
        const int g = blockIdx.x & (NGROUPS - 1);
        const int s = blockIdx.x >> 2;               // slice 0..NSLICES-1
        const int lo = g * DST_PER_GROUP;
        const int e0 = s * 256 + tid;
        int d[KMAX];
        bool mk[KMAX];
#pragma unroll
        for (int k = 0; k < KMAX; ++k) {
            int e = e0 + k * FSTRIDE;
            int dv = (e < N_EDGES) ? dst[e] : -1;
            d[k] = dv;
            mk[k] = ((uint)(dv - lo) < (uint)DST_PER_GROUP);
        }
        float wv5[KMAX];
        int sv5[KMAX];
#pragma unroll
        for (int k = 0; k < KMAX; ++k)
            if (mk[k]) {
                int e = e0 + k * FSTRIDE;
                wv5[k] = __builtin_nontemporal_load(w + e);
                sv5[k] = __builtin_nontemporal_load(src + e);
            }
        int r5[KMAX];
#pragma unroll
        for (int k = 0; k < KMAX; ++k)
            if (mk[k]) r5[k] = atomicAdd(&deg[d[k]], 1);
#pragma unroll
        for (int k = 0; k < KMAX; ++k)
            if (mk[k]) {
                uint hw = (uint)__half_as_ushort(__float2half_rn(wv5[k]));
                uint payload = (uint)sv5[k] | (hw << 16);
                int r = r5[k];
                if (r < CAP) {
                    csr[(d[k] << 5) + r] = payload;
                } else {
                    int si = atomicAdd(spillCnt, 1);
                    if (si < SPILL_MAX) spill[si] = make_uint2((uint)d[k], payload);
                }
            }
        return;
    }

    if (blockIdx.x >= FILL_BLOCKS + MM_BLOCKS) {
        // ---------- weight-split prep ----------
        if (blockIdx.x == FILL_BLOCKS + MM_BLOCKS) {
            for (int idx = tid; idx < D * D; idx += 256) {
                int k = idx >> 6, c = idx & 63;
                float wv = W2[idx];
                ushort hi = f2bf(wv);
                W2T2[(size_t)c * D + k] = (short)hi;
                W2T2[(size_t)(D + c) * D + k] = (short)f2bf(wv - bf2f(hi));
            }
        } else {
            for (int idx = tid; idx < NCT * 16 * D; idx += 256) {
                int jj = idx >> 6, k = idx & 63;
                float wv = (jj < DHID) ? Wd[k * DHID + jj] : 0.f;
                ushort hi = f2bf(wv);
                WdT2[(size_t)jj * D + k] = (short)hi;
                WdT2[(size_t)(NCT * 16 + jj) * D + k] = (short)f2bf(wv - bf2f(hi));
            }
        }
        return;
    }

    // ---------- mfma_l1 path ----------
    for (int idx = tid; idx < D * D; idx += 256) {
        int k = idx >> 6, c = idx & 63;
        float wv = W[idx];
        ushort hi = f2bf(wv);
        sBT[0][c][k] = (short)hi;
        sBT[1][c][k] = (short)f2bf(wv - bf2f(hi));
    }
    __syncthreads();
    int wv_ = tid >> 6, lane = tid & 63, quad = lane >> 4, m = lane & 15;
    int tile = min((blockIdx.x - FILL_BLOCKS) * 4 + wv_, NTILES - 1);  // clamp (dup stores ok)
    int node0 = tile * 16;

    f32x4 acc[4] = {{0,0,0,0},{0,0,0,0},{0,0,0,0},{0,0,0,0}};
#pragma unroll
    for (int kt = 0; kt < 2; ++kt) {
        int k0 = kt * 32 + quad * 8;
        const float* xp = X + ((size_t)(node0 + m) << 6) + k0;
        f32x4 xa = __builtin_nontemporal_load((const f32x4*)xp);   // NT: X read-once
        f32x4 xb = __builtin_nontemporal_load((const f32x4*)(xp + 4));
        float xv[8] = {xa[0], xa[1], xa[2], xa[3], xb[0], xb[1], xb[2], xb[3]};
        s16x8 ahi, alo;
#pragma unroll
        for (int jj = 0; jj < 8; ++jj) {
            ushort hi = f2bf(xv[jj]);
            ahi[jj] = (short)hi;
            alo[jj] = (short)f2bf(xv[jj] - bf2f(hi));
        }
#pragma unroll
        for (int ct = 0; ct < 4; ++ct) {
            int n = ct * 16 + m;
            s16x8 bhi = *((const s16x8*)&sBT[0][n][k0]);
            s16x8 blo = *((const s16x8*)&sBT[1][n][k0]);
            acc[ct] = MFMA16(ahi, bhi, acc[ct]);
            acc[ct] = MFMA16(ahi, blo, acc[ct]);
            acc[ct] = MFMA16(alo, bhi, acc[ct]);
        }
    }
    __syncthreads();   // safe to alias rep over sBT
    short (*rep)[16][72] = (short(*)[16][72])&sBT[0][0][0];
#pragma unroll
    for (int ct = 0; ct < 4; ++ct)
#pragma unroll
        for (int r = 0; r < 4; ++r)
            rep[wv_][quad * 4 + r][ct * 16 + m] = (short)f2bf(acc[ct][r]);
#pragma unroll
    for (int half = 0; half < 2; ++half) {
        int r = (lane >> 3) + half * 8;
        int c0 = (lane & 7) * 8;
        s16x8 v = *((const s16x8*)&rep[wv_][r][c0]);
        ushort* pl = (c0 < 32) ? H1a : H1b;
        *((s16x8*)(pl + ((size_t)(node0 + r) << 5) + (c0 & 31))) = v;
    }
}

// ---- gather pass (layer 1): one feature plane -> act plane, bias+swish ----
// 8 nodes/block, XCD-chunked so csr/deg/act slices are XCD-local; the shared
// random-read plane (3.2MB) becomes L2-resident per XCD.
__global__ __launch_bounds__(256) void gather_pass_act(const ushort* __restrict__ plane,
                                                       const int* __restrict__ deg,
                                                       const uint* __restrict__ csr,
                                                       const int* __restrict__ spillCnt,
                                                       const uint2* __restrict__ spill,
                                                       const float* __restrict__ bias32,
                                                       ushort* __restrict__ actPlane) {
    int tid = threadIdx.x;
    int wave = tid >> 6, lane = tid & 63;
    int h = lane >> 5, j = (lane >> 2) & 7, fgp = lane & 3;
    int node = swz6250(blockIdx.x) * 8 + wave * 2 + h;
    const uint* bucket = csr + ((size_t)node << 5);
    int degv = min(deg[node], CAP);

    float acc[8];
    gather32(plane, bucket, degv, j * 4, fgp, acc);
    if (j == 0) {
        add_spills32(plane, spillCnt, spill, node, fgp, acc);
        float4 ba = ((const float4*)bias32)[fgp * 2];
        float4 bb = ((const float4*)bias32)[fgp * 2 + 1];
        float r0 = swishf(acc[0] + ba.x);
        float r1 = swishf(acc[1] + ba.y);
        float r2 = swishf(acc[2] + ba.z);
        float r3 = swishf(acc[3] + ba.w);
        float r4 = swishf(acc[4] + bb.x);
        float r5 = swishf(acc[5] + bb.y);
        float r6 = swishf(acc[6] + bb.z);
        float r7 = swishf(acc[7] + bb.w);
        u32x4 u;
        u[0] = (uint)f2bf(r0) | ((uint)f2bf(r1) << 16);
        u[1] = (uint)f2bf(r2) | ((uint)f2bf(r3) << 16);
        u[2] = (uint)f2bf(r4) | ((uint)f2bf(r5) << 16);
        u[3] = (uint)f2bf(r6) | ((uint)f2bf(r7) << 16);
        __builtin_nontemporal_store(u, (u32x4*)(actPlane + ((size_t)node << 5) + (fgp << 3)));
    }
}

// ---- gather pass (layer 2): act plane -> fp32 agg plane (no bias/swish) ----
__global__ __launch_bounds__(256) void gather_pass_agg(const ushort* __restrict__ plane,
                                                       const int* __restrict__ deg,
                                                       const uint* __restrict__ csr,
                                                       const int* __restrict__ spillCnt,
                                                       const uint2* __restrict__ spill,
                                                       float* __restrict__ aggPlane) {
    int tid = threadIdx.x;
    int wave = tid >> 6, lane = tid & 63;
    int h = lane >> 5, j = (lane >> 2) & 7, fgp = lane & 3;
    int node = swz6250(blockIdx.x) * 8 + wave * 2 + h;
    const uint* bucket = csr + ((size_t)node << 5);
    int degv = min(deg[node], CAP);

    float acc[8];
    gather32(plane, bucket, degv, j * 4, fgp, acc);
    if (j == 0) {
        add_spills32(plane, spillCnt, spill, node, fgp, acc);
        f32x4 u0 = {acc[0], acc[1], acc[2], acc[3]};
        f32x4 u1 = {acc[4], acc[5], acc[6], acc[7]};
        float* p = aggPlane + ((size_t)node << 5) + (fgp << 3);
        __builtin_nontemporal_store(u0, (f32x4*)p);
        __builtin_nontemporal_store(u1, (f32x4*)(p + 4));
    }
}

// ---- mm_head: stream agg planes -> act2 = swish(agg@W2+b2) -> MLP head ----
__global__ __launch_bounds__(256) void mm_head(const float* __restrict__ aggA,
                                               const float* __restrict__ aggB,
                                               const short* __restrict__ W2T2,
                                               const float* __restrict__ b2,
                                               const short* __restrict__ WdT2,
                                               const float* __restrict__ bd,
                                               const float* __restrict__ Wo,
                                               const float* __restrict__ bo,
                                               float* __restrict__ out) {
    __shared__ __align__(16) float sAgg[16][72];
    __shared__ __align__(16) short sAct2[16][72];
    __shared__ float sPart[4][16];
    int tid = threadIdx.x;
    int wv = tid >> 6, lane = tid & 63;
    int quad = lane >> 4, m = lane & 15;
    int node0 = blockIdx.x * 16;

    {   // coalesced plane -> LDS (one float4 per thread)
        int idx = tid * 4;
        int nl = idx >> 6, f = idx & 63;
        const float* p = (f < 32) ? (aggA + ((size_t)(node0 + nl) << 5) + f)
                                  : (aggB + ((size_t)(node0 + nl) << 5) + (f - 32));
        float4 v = *((const float4*)p);
        *((float4*)&sAgg[nl][f]) = v;
    }
    __syncthreads();

    // ---- phase A: act2 = swish(agg @ W2 + b2), wave wv -> col-tile wv ----
    {
        f32x4 acc = {0, 0, 0, 0};
        int n = wv * 16 + m;
#pragma unroll
        for (int kt = 0; kt < 2; ++kt) {
            int k0 = kt * 32 + quad * 8;
            float4 xa = *((const float4*)&sAgg[m][k0]);
            float4 xb = *((const float4*)&sAgg[m][k0 + 4]);
            float xv[8] = {xa.x, xa.y, xa.z, xa.w, xb.x, xb.y, xb.z, xb.w};
            s16x8 ahi, alo;
#pragma unroll
            for (int jj = 0; jj < 8; ++jj) {
                ushort hi = f2bf(xv[jj]);
                ahi[jj] = (short)hi;
                alo[jj] = (short)f2bf(xv[jj] - bf2f(hi));
            }
            s16x8 bhi = *((const s16x8*)(W2T2 + (size_t)n * D + k0));
            s16x8 blo = *((const s16x8*)(W2T2 + (size_t)(D + n) * D + k0));
            acc = MFMA16(ahi, bhi, acc);
            acc = MFMA16(ahi, blo, acc);
            acc = MFMA16(alo, bhi, acc);
        }
        float bv = b2[n];
#pragma unroll
        for (int r = 0; r < 4; ++r)
            sAct2[quad * 4 + r][n] = (short)f2bf(swishf(acc[r] + bv));
    }
    __syncthreads();

    // ---- phase B: head over col-tiles {wv, wv+4} ----
    float part[4] = {0, 0, 0, 0};
#pragma unroll
    for (int cc = 0; cc < 2; ++cc) {
        int ct = wv + cc * 4;
        if (ct < NCT) {
            f32x4 acc = {0, 0, 0, 0};
            int n = ct * 16 + m;
#pragma unroll
            for (int kt = 0; kt < 2; ++kt) {
                int k0 = kt * 32 + quad * 8;
                s16x8 a = *((const s16x8*)&sAct2[m][k0]);
                s16x8 bhi = *((const s16x8*)(WdT2 + (size_t)n * D + k0));
                s16x8 blo = *((const s16x8*)(WdT2 + (size_t)(NCT * 16 + n) * D + k0));
                acc = MFMA16(a, bhi, acc);
                acc = MFMA16(a, blo, acc);
            }
            float bdv = (n < DHID) ? bd[n] : 0.f;
            float wov = (n < DHID) ? Wo[n] : 0.f;
#pragma unroll
            for (int r = 0; r < 4; ++r)
                part[r] = fmaf(swishf(acc[r] + bdv), wov, part[r]);
        }
    }
#pragma unroll
    for (int r = 0; r < 4; ++r) {
        part[r] += __shfl_xor(part[r], 1, 64);
        part[r] += __shfl_xor(part[r], 2, 64);
        part[r] += __shfl_xor(part[r], 4, 64);
        part[r] += __shfl_xor(part[r], 8, 64);
    }
    if (m == 0) {
#pragma unroll
        for (int r = 0; r < 4; ++r)
            sPart[wv][quad * 4 + r] = part[r];
    }
    __syncthreads();
    if (tid < 16) {
        float z = sPart[0][tid] + sPart[1][tid] + sPart[2][tid] + sPart[3][tid] + bo[0];
        out[node0 + tid] = 1.f / (1.f + __expf(-z));
    }
}

extern "C" void kernel_launch(void* const* d_in, const int* in_sizes, int n_in,
                              void* d_out, int out_size, void* d_ws, size_t ws_size,
                              hipStream_t stream) {
    const float* x   = (const float*)d_in[0];
    const int* esrc  = (const int*)d_in[1];
    const int* edst  = (const int*)d_in[2];
    const float* ew  = (const float*)d_in[3];
    const float* W1  = (const float*)d_in[4];
    const float* b1  = (const float*)d_in[5];
    const float* W2  = (const float*)d_in[6];
    const float* b2  = (const float*)d_in[7];
    const float* Wd  = (const float*)d_in[8];
    const float* bd  = (const float*)d_in[9];
    const float* Wo  = (const float*)d_in[10];
    const float* bo  = (const float*)d_in[11];
    float* out = (float*)d_out;

    char* ws = (char*)d_ws;
    ushort* H1a   = (ushort*)ws; ws += (size_t)N_NODES * 32 * sizeof(ushort);  // 3.2 MB
    ushort* H1b   = (ushort*)ws; ws += (size_t)N_NODES * 32 * sizeof(ushort);  // 3.2 MB
    ushort* act1a = (ushort*)ws; ws += (size_t)N_NODES * 32 * sizeof(ushort);  // 3.2 MB
    ushort* act1b = (ushort*)ws; ws += (size_t)N_NODES * 32 * sizeof(ushort);  // 3.2 MB
    float* aggA   = (float*)ws;  ws += (size_t)N_NODES * 32 * sizeof(float);   // 6.4 MB
    float* aggB   = (float*)ws;  ws += (size_t)N_NODES * 32 * sizeof(float);   // 6.4 MB
    uint* csr     = (uint*)ws;   ws += (size_t)N_NODES * CAP * sizeof(uint);   // 6.4 MB (not zeroed)
    int* deg      = (int*)ws;    ws += (size_t)N_NODES * sizeof(int);          // 200 KB
    int* spillCnt = (int*)ws;    ws += 4 * sizeof(int);                        // adj. to deg
    uint2* spill  = (uint2*)ws;  ws += (size_t)SPILL_MAX * sizeof(uint2);      // 64 KB (not zeroed)
    short* W2T2   = (short*)ws;  ws += (size_t)2 * D * D * sizeof(short);      // 16 KB
    short* WdT2   = (short*)ws;  ws += (size_t)2 * NCT * 16 * D * sizeof(short); // 28.7 KB

    // ---- zero deg + spillCnt in one memset (contiguous) ----
    hipMemsetAsync(deg, 0, (size_t)(N_NODES + 4) * sizeof(int), stream);

    // ---- fused: XCD-partitioned fill + layer-1 matmul (plane-split) + weight prep ----
    fill_and_l1<<<FILL_BLOCKS + MM_BLOCKS + 2, 256, 0, stream>>>(
        esrc, edst, ew, deg, csr, spillCnt, spill, x, W1, W2, Wd, W2T2, WdT2, H1a, H1b);

    // ---- layer-1 gather: two feature-plane passes (each 3.2MB -> L2-resident) ----
    gather_pass_act<<<GP_BLOCKS, 256, 0, stream>>>(H1a, deg, csr, spillCnt, spill, b1, act1a);
    gather_pass_act<<<GP_BLOCKS, 256, 0, stream>>>(H1b, deg, csr, spillCnt, spill, b1 + 32, act1b);

    // ---- layer-2 gather: two plane passes -> fp32 agg planes ----
    gather_pass_agg<<<GP_BLOCKS, 256, 0, stream>>>(act1a, deg, csr, spillCnt, spill, aggA);
    gather_pass_agg<<<GP_BLOCKS, 256, 0, stream>>>(act1b, deg, csr, spillCnt, spill, aggB);

    // ---- W2 matmul + swish + MLP head (streams agg planes) ----
    mm_head<<<NTILES, 256, 0, stream>>>(aggA, aggB, W2T2, b2, WdT2, bd, Wo, bo, out);
}